// Round 18
// baseline (1831.455 us; speedup 1.0000x reference)
//
#include <hip/hip_runtime.h>

typedef __bf16 bf16;
typedef __bf16 bf16x8 __attribute__((ext_vector_type(8)));
typedef float f32x4 __attribute__((ext_vector_type(4)));

#define NN 87381
#define NINT 21845
#define NLEAF 65536
#define LEAF_START 21845

__device__ __forceinline__ float sigmoidf_(float x) {
    return 1.0f / (1.0f + __expf(-x));
}
__device__ __forceinline__ float tanhf_(float x) {
    return 1.0f - 2.0f / (__expf(2.0f * x) + 1.0f);
}

// async 16B global -> LDS (lane-contiguous dest required)
__device__ __forceinline__ void gload_lds16(const bf16* g, bf16* l) {
    __builtin_amdgcn_global_load_lds(
        (const __attribute__((address_space(1))) unsigned int*)g,
        (__attribute__((address_space(3))) unsigned int*)l, 16, 0, 0);
}

// Bijective XCD-chunked blockIdx swizzle (m204).
__device__ __forceinline__ int xcd_swz(int bid, int nwg) {
    int q = nwg >> 3, r = nwg & 7;
    int x = bid & 7, i = bid >> 3;
    return (x < r ? x * (q + 1) : r * (q + 1) + (x - r) * q) + i;
}

// XOR-swizzled LDS chunk index for (row, kchunk) on a [R][64] bf16 tile
// (conflict-free: R4/R8 measured SQ_LDS_BANK_CONFLICT == 0).
#define SWZ(r, kc) ((((r) << 3) | ((kc) ^ ((r) & 7))) << 3)

// ---------------------------------------------------------------------------
// W (512 x NR fp32, row-major) -> Wt (NR x 512 bf16)
__global__ void tconv_kernel(const float* __restrict__ W, bf16* __restrict__ Wt,
                             int NR, int total) {
    int idx = blockIdx.x * 256 + threadIdx.x;
    if (idx >= total) return;
    int n = idx >> 9;
    int k = idx & 511;
    Wt[idx] = (bf16)W[(size_t)k * NR + n];
}

// x fp32 -> bf16, vectorized (4 floats / thread)
__global__ void convx_kernel(const float* __restrict__ X, bf16* __restrict__ Y, int total4) {
    int idx = blockIdx.x * 256 + threadIdx.x;
    if (idx >= total4) return;
    const float4 f = *reinterpret_cast<const float4*>(X + (size_t)idx * 4);
    bf16 o[4] = {(bf16)f.x, (bf16)f.y, (bf16)f.z, (bf16)f.w};
    *reinterpret_cast<ushort2*>(Y + (size_t)idx * 4 + 0) = *reinterpret_cast<ushort2*>(&o[0]);
    *reinterpret_cast<ushort2*>(Y + (size_t)idx * 4 + 2) = *reinterpret_cast<ushort2*>(&o[2]);
}

// ---------------------------------------------------------------------------
// 2x4 MFMA compute core (8-wave blocks: wave tile 32 rows x 64 cols), K=64.
#define MFMA_COMPUTE_2x4(As, Bs, acc, wm, wn, lm, quad)                          \
    _Pragma("unroll")                                                            \
    for (int kk = 0; kk < 64; kk += 32) {                                        \
        const int kc_ = (kk >> 3) + quad;                                        \
        bf16x8 areg[2], breg[4];                                                 \
        _Pragma("unroll")                                                        \
        for (int mi = 0; mi < 2; ++mi)                                           \
            areg[mi] = *reinterpret_cast<const bf16x8*>(                         \
                &(As)[SWZ(wm + mi * 16 + lm, kc_)]);                             \
        _Pragma("unroll")                                                        \
        for (int ni = 0; ni < 4; ++ni)                                           \
            breg[ni] = *reinterpret_cast<const bf16x8*>(                         \
                &(Bs)[SWZ(wn + ni * 16 + lm, kc_)]);                             \
        _Pragma("unroll")                                                        \
        for (int mi = 0; mi < 2; ++mi)                                           \
            _Pragma("unroll")                                                    \
            for (int ni = 0; ni < 4; ++ni)                                       \
                acc[mi][ni] = __builtin_amdgcn_mfma_f32_16x16x32_bf16(           \
                    areg[mi], breg[ni], acc[mi][ni], 0, 0, 0);                   \
    }

// Plain GEMM: C[M x N] = A[M x K] @ Bt[N x K]^T + b1 + b2 (Bt ld = bstride).
// 512 threads / 8 waves, 128x128 block tile, wave tile 32x64 -> 32 acc regs.
// BK=64 double-buffered, hoisted staging pointers (advance by t*64).
__global__ __launch_bounds__(512)
void gemm_kernel(const bf16* __restrict__ A, const bf16* __restrict__ Bt,
                 int bstride, int K, int ntiles,
                 float* __restrict__ Cf, bf16* __restrict__ Cb,
                 const float* __restrict__ bias1, const float* __restrict__ bias2,
                 int M, int N, int relu, int swz)
{
    __shared__ __align__(16) bf16 As[2][128 * 64];
    __shared__ __align__(16) bf16 Bs[2][128 * 64];
    const int tid  = threadIdx.x;
    const int wave = tid >> 6;
    const int lane = tid & 63;
    int bid = blockIdx.x;
    if (swz) bid = xcd_swz(bid, (int)gridDim.x);
    const int bm = (bid / ntiles) * 128;
    const int bn = (bid % ntiles) * 128;
    const int wm = (wave & 3) * 32;
    const int wn = (wave >> 2) * 64;
    const int lm   = lane & 15;
    const int quad = lane >> 4;

    f32x4 acc[2][4];
#pragma unroll
    for (int i = 0; i < 2; ++i)
#pragma unroll
        for (int j = 0; j < 4; ++j) acc[i][j] = (f32x4){0.f, 0.f, 0.f, 0.f};

    // hoisted per-chunk staging pointers/offsets
    const bf16* aptr[2];
    const bf16* bptr[2];
    int loff[2];
#pragma unroll
    for (int i = 0; i < 2; ++i) {
        int c   = i * 512 + tid;           // 1024 chunks (128 rows x 8)
        int r   = c >> 3;
        int kc8 = ((c & 7) ^ (r & 7)) << 3;
        int gr  = bm + r; gr = (gr < M) ? gr : (M - 1);
        aptr[i] = A + (size_t)gr * K + kc8;
        bptr[i] = Bt + (size_t)(bn + r) * bstride + kc8;
        loff[i] = c << 3;
    }

    auto stage = [&](int buf, int t) {
        const int kofs = t << 6;
#pragma unroll
        for (int i = 0; i < 2; ++i)
            gload_lds16(aptr[i] + kofs, &As[0][0] + buf * (128 * 64) + loff[i]);
#pragma unroll
        for (int i = 0; i < 2; ++i)
            gload_lds16(bptr[i] + kofs, &Bs[0][0] + buf * (128 * 64) + loff[i]);
    };

    const int nk = K >> 6;
    stage(0, 0);
    __syncthreads();
    int cur = 0;
    for (int t = 0; t < nk; ++t) {
        if (t + 1 < nk) stage(cur ^ 1, t + 1);
        MFMA_COMPUTE_2x4(As[cur], Bs[cur], acc, wm, wn, lm, quad);
        __syncthreads();   // drains prefetch vmcnt AFTER compute
        cur ^= 1;
    }

#pragma unroll
    for (int ni = 0; ni < 4; ++ni) {
        int col = bn + wn + ni * 16 + lm;
        float bsum = (bias1 ? bias1[col] : 0.f) + (bias2 ? bias2[col] : 0.f);
#pragma unroll
        for (int mi = 0; mi < 2; ++mi) {
#pragma unroll
            for (int r = 0; r < 4; ++r) {
                int row = bm + wm + mi * 16 + quad * 4 + r;
                if (row < M) {
                    float v = acc[mi][ni][r] + bsum;
                    if (relu) v = (v > 0.f) ? v : 0.f;
                    if (Cf) Cf[(size_t)row * N + col] = v;
                    else    Cb[(size_t)row * N + col] = (bf16)v;
                }
            }
        }
    }
}

// ---------------------------------------------------------------------------
// Leaf kernel: fused 3-gate IOU GEMM (K=512) + cell epilogue + hs producer.
// A = leaf h rows; B = gate-major [1536][512] (W_ioux^T). No fcs, no xout.
__global__ __launch_bounds__(512)
void leaf_kernel(const bf16* __restrict__ A, const bf16* __restrict__ wiou,
                 const float* __restrict__ bx1, const float* __restrict__ bx2,
                 bf16* __restrict__ hout, bf16* __restrict__ cellout,
                 bf16* __restrict__ hsout, int M, int swz)
{
    __shared__ __align__(16) bf16 As[2][128 * 64];
    __shared__ __align__(16) bf16 Bs[2][3 * 64 * 64];
    const int tid  = threadIdx.x;
    const int wave = tid >> 6;
    const int lane = tid & 63;
    int bid = blockIdx.x;
    if (swz) bid = xcd_swz(bid, (int)gridDim.x);
    const int bm = (bid >> 3) * 128;
    const int bn = (bid & 7) * 64;
    if (bm >= M) return;
    const int wm   = (wave & 3) * 32;
    const int wn   = (wave >> 2) * 32;
    const int lm   = lane & 15;
    const int quad = lane >> 4;

    f32x4 acc[3][2][2];
#pragma unroll
    for (int g = 0; g < 3; ++g)
#pragma unroll
        for (int i = 0; i < 2; ++i)
#pragma unroll
            for (int j = 0; j < 2; ++j) acc[g][i][j] = (f32x4){0.f, 0.f, 0.f, 0.f};

    const bf16* aptr[2];
    int aoff[2];
#pragma unroll
    for (int i = 0; i < 2; ++i) {
        int c   = i * 512 + tid;
        int r   = c >> 3;
        int kc8 = ((c & 7) ^ (r & 7)) << 3;
        int gr  = bm + r; gr = (gr < M) ? gr : (M - 1);
        aptr[i] = A + ((size_t)gr << 9) + kc8;
        aoff[i] = c << 3;
    }
    const bf16* bptr[3];
    int boff[3];
#pragma unroll
    for (int i = 0; i < 3; ++i) {
        int c   = i * 512 + tid;
        int g   = c >> 9;
        int cg  = c & 511;
        int r   = cg >> 3;
        int kc8 = ((cg & 7) ^ (r & 7)) << 3;
        bptr[i] = wiou + (size_t)(g * 512 + bn + r) * 512 + kc8;
        boff[i] = c << 3;
    }

    auto stage = [&](int buf, int t) {
        const int kofs = t << 6;
#pragma unroll
        for (int i = 0; i < 2; ++i)
            gload_lds16(aptr[i] + kofs, &As[0][0] + buf * (128 * 64) + aoff[i]);
#pragma unroll
        for (int i = 0; i < 3; ++i)
            gload_lds16(bptr[i] + kofs, &Bs[0][0] + buf * (3 * 64 * 64) + boff[i]);
    };

    stage(0, 0);
    __syncthreads();
    int cur = 0;
    for (int t = 0; t < 8; ++t) {
        if (t + 1 < 8) stage(cur ^ 1, t + 1);
#pragma unroll
        for (int kk = 0; kk < 64; kk += 32) {
            const int kc_ = (kk >> 3) + quad;
            bf16x8 areg[2];
#pragma unroll
            for (int mi = 0; mi < 2; ++mi)
                areg[mi] = *reinterpret_cast<const bf16x8*>(
                    &As[cur][SWZ(wm + mi * 16 + lm, kc_)]);
            bf16x8 breg[3][2];
#pragma unroll
            for (int g = 0; g < 3; ++g)
#pragma unroll
                for (int ni = 0; ni < 2; ++ni)
                    breg[g][ni] = *reinterpret_cast<const bf16x8*>(
                        &Bs[cur][g * 4096 + SWZ(wn + ni * 16 + lm, kc_)]);
#pragma unroll
            for (int g = 0; g < 3; ++g)
#pragma unroll
                for (int mi = 0; mi < 2; ++mi)
#pragma unroll
                    for (int ni = 0; ni < 2; ++ni)
                        acc[g][mi][ni] = __builtin_amdgcn_mfma_f32_16x16x32_bf16(
                            areg[mi], breg[g][ni], acc[g][mi][ni], 0, 0, 0);
        }
        __syncthreads();
        cur ^= 1;
    }

#pragma unroll
    for (int ni = 0; ni < 2; ++ni) {
        int col = bn + wn + ni * 16 + lm;
        float bi = bx1[col]        + bx2[col];
        float bo = bx1[col + 512]  + bx2[col + 512];
        float bu = bx1[col + 1024] + bx2[col + 1024];
#pragma unroll
        for (int mi = 0; mi < 2; ++mi) {
            int rbase = bm + wm + mi * 16 + quad * 4;
            float hsum = 0.f;
#pragma unroll
            for (int r = 0; r < 4; ++r) {
                int row = rbase + r;
                if (row < M) {
                    float i_ = sigmoidf_(acc[0][mi][ni][r] + bi);
                    float o_ = sigmoidf_(acc[1][mi][ni][r] + bo);
                    float u_ = tanhf_(acc[2][mi][ni][r] + bu);
                    float c  = i_ * u_;
                    bf16 hb  = (bf16)(o_ * tanhf_(c));
                    cellout[(size_t)row * 512 + col] = (bf16)c;
                    hout[(size_t)row * 512 + col] = hb;
                    hsum += (float)hb;
                }
            }
            if (hsout && rbase < M)
                hsout[(size_t)(rbase >> 2) * 512 + col] = (bf16)hsum;
        }
    }
}

// ---------------------------------------------------------------------------
// MERGED per-level kernel: Phase A (CF f-gates -> fcsum slice) + Phase B (IOU
// + cell epilogue + hs producer), one launch per tree level.
// Block (bm parents x 64-col slice bn): the fcsum[bm..bm+128][bn*64..+64] this
// block's Phase B needs is EXACTLY what its Phase A produces (rows/cols
// partition across blocks with no redundancy). fcsum round-trips through
// global but is intra-block: __syncthreads in Phase B orders the accesses.
__global__ __launch_bounds__(512)
void level_kernel(const bf16* __restrict__ hs, const bf16* __restrict__ hc,
                  const bf16* __restrict__ cellc,
                  const bf16* __restrict__ wih, const bf16* __restrict__ wfh,
                  const bf16* __restrict__ xout,
                  const float* __restrict__ bx1, const float* __restrict__ bx2,
                  const float* __restrict__ bf1, const float* __restrict__ bf2,
                  float* __restrict__ fcsum,
                  bf16* __restrict__ hout, bf16* __restrict__ cellout,
                  bf16* __restrict__ hsout, int E, int swz)
{
    __shared__ __align__(16) bf16 As[2][128 * 64];
    __shared__ __align__(16) bf16 Bs[2][3 * 64 * 64];
    const int tid  = threadIdx.x;
    const int wave = tid >> 6;
    const int lane = tid & 63;
    int bid = blockIdx.x;
    if (swz) bid = xcd_swz(bid, (int)gridDim.x);
    const int bm = (bid >> 3) * 128;       // parent-row tile
    const int bn = (bid & 7);              // 64-col slice index in [0,8)
    if (bm >= E) return;
    const int lm   = lane & 15;
    const int quad = lane >> 4;
    const int M4   = 4 * E;

    // ================= Phase A: children f-gates -> fcsum ==================
    {
        const int wmA = (wave & 3) * 32;   // 8 waves over 128 rows x 64 cols
        const int wnA = (wave >> 2) * 32;
        // B tile: wfh rows [bn*64, +64), 512 chunks (1 per thread)
        const int rb  = tid >> 3;
        const int kcb = ((tid & 7) ^ (rb & 7)) << 3;
        const bf16* bfp = wfh + (size_t)(bn * 64 + rb) * 512 + kcb;
        const int  bofs = tid << 3;

        for (int s = 0; s < 4; ++s) {      // 4 sub-chunks of 128 child rows
            const bf16* aptrA[2]; int aoffA[2];
#pragma unroll
            for (int i = 0; i < 2; ++i) {
                int c   = i * 512 + tid;
                int r   = c >> 3;
                int kc8 = ((c & 7) ^ (r & 7)) << 3;
                int gr  = 4 * bm + 128 * s + r; gr = (gr < M4) ? gr : (M4 - 1);
                aptrA[i] = hc + ((size_t)gr << 9) + kc8;
                aoffA[i] = c << 3;
            }
            f32x4 accA[2][2];
#pragma unroll
            for (int i = 0; i < 2; ++i)
#pragma unroll
                for (int j = 0; j < 2; ++j) accA[i][j] = (f32x4){0.f, 0.f, 0.f, 0.f};

            auto stageA = [&](int buf, int t) {
                const int kofs = t << 6;
#pragma unroll
                for (int i = 0; i < 2; ++i)
                    gload_lds16(aptrA[i] + kofs, &As[0][0] + buf * (128 * 64) + aoffA[i]);
                gload_lds16(bfp + kofs, &Bs[0][0] + buf * (3 * 64 * 64) + bofs);
            };

            stageA(0, 0);
            __syncthreads();
            int cur = 0;
            for (int t = 0; t < 8; ++t) {
                if (t + 1 < 8) stageA(cur ^ 1, t + 1);
#pragma unroll
                for (int kk = 0; kk < 64; kk += 32) {
                    const int kc_ = (kk >> 3) + quad;
                    bf16x8 ar[2], br[2];
#pragma unroll
                    for (int mi = 0; mi < 2; ++mi)
                        ar[mi] = *reinterpret_cast<const bf16x8*>(
                            &As[cur][SWZ(wmA + mi * 16 + lm, kc_)]);
#pragma unroll
                    for (int ni = 0; ni < 2; ++ni)
                        br[ni] = *reinterpret_cast<const bf16x8*>(
                            &Bs[cur][SWZ(wnA + ni * 16 + lm, kc_)]);
#pragma unroll
                    for (int mi = 0; mi < 2; ++mi)
#pragma unroll
                        for (int ni = 0; ni < 2; ++ni)
                            accA[mi][ni] = __builtin_amdgcn_mfma_f32_16x16x32_bf16(
                                ar[mi], br[ni], accA[mi][ni], 0, 0, 0);
                }
                __syncthreads();
                cur ^= 1;
            }
            // epilogue: per-lane sibling-group f*cell sums -> fcsum (no LDS)
#pragma unroll
            for (int ni = 0; ni < 2; ++ni) {
                int col = bn * 64 + wnA + ni * 16 + lm;
                float bsum = bf1[col] + bf2[col];
#pragma unroll
                for (int mi = 0; mi < 2; ++mi) {
                    int lr = 128 * s + wmA + mi * 16 + quad * 4;  // local child row
                    int p  = bm + (lr >> 2);
                    if (p < E) {
                        float pf = (float)xout[(size_t)p * 2048 + 1536 + col] + bsum;
                        float fc = 0.f;
#pragma unroll
                        for (int r = 0; r < 4; ++r) {
                            int cr = 4 * bm + lr + r;
                            fc += sigmoidf_(accA[mi][ni][r] + pf) *
                                  (float)cellc[(size_t)cr * 512 + col];
                        }
                        fcsum[(size_t)p * 512 + col] = fc;
                    }
                }
            }
        }
    }

    // ================= Phase B: IOU + cell epilogue ========================
    const int wm = (wave & 3) * 32;
    const int wn = (wave >> 2) * 32;
    const int bncol = bn * 64;

    f32x4 acc[3][2][2];
#pragma unroll
    for (int g = 0; g < 3; ++g)
#pragma unroll
        for (int i = 0; i < 2; ++i)
#pragma unroll
            for (int j = 0; j < 2; ++j) acc[g][i][j] = (f32x4){0.f, 0.f, 0.f, 0.f};

    const bf16* aptr[2];
    int aoff[2];
#pragma unroll
    for (int i = 0; i < 2; ++i) {
        int c   = i * 512 + tid;
        int r   = c >> 3;
        int kc8 = ((c & 7) ^ (r & 7)) << 3;
        int gr  = bm + r; gr = (gr < E) ? gr : (E - 1);
        aptr[i] = hs + ((size_t)gr << 9) + kc8;
        aoff[i] = c << 3;
    }
    const bf16* bptr[3];
    int boff[3];
#pragma unroll
    for (int i = 0; i < 3; ++i) {
        int c   = i * 512 + tid;
        int g   = c >> 9;
        int cg  = c & 511;
        int r   = cg >> 3;
        int kc8 = ((cg & 7) ^ (r & 7)) << 3;
        bptr[i] = wih + (size_t)(g * 512 + bncol + r) * 512 + kc8;
        boff[i] = c << 3;
    }

    auto stage = [&](int buf, int t) {
        const int kofs = t << 6;
#pragma unroll
        for (int i = 0; i < 2; ++i)
            gload_lds16(aptr[i] + kofs, &As[0][0] + buf * (128 * 64) + aoff[i]);
#pragma unroll
        for (int i = 0; i < 3; ++i)
            gload_lds16(bptr[i] + kofs, &Bs[0][0] + buf * (3 * 64 * 64) + boff[i]);
    };

    stage(0, 0);
    __syncthreads();
    int cur = 0;
    for (int t = 0; t < 8; ++t) {
        if (t + 1 < 8) stage(cur ^ 1, t + 1);
#pragma unroll
        for (int kk = 0; kk < 64; kk += 32) {
            const int kc_ = (kk >> 3) + quad;
            bf16x8 areg[2];
#pragma unroll
            for (int mi = 0; mi < 2; ++mi)
                areg[mi] = *reinterpret_cast<const bf16x8*>(
                    &As[cur][SWZ(wm + mi * 16 + lm, kc_)]);
            bf16x8 breg[3][2];
#pragma unroll
            for (int g = 0; g < 3; ++g)
#pragma unroll
                for (int ni = 0; ni < 2; ++ni)
                    breg[g][ni] = *reinterpret_cast<const bf16x8*>(
                        &Bs[cur][g * 4096 + SWZ(wn + ni * 16 + lm, kc_)]);
#pragma unroll
            for (int g = 0; g < 3; ++g)
#pragma unroll
                for (int mi = 0; mi < 2; ++mi)
#pragma unroll
                    for (int ni = 0; ni < 2; ++ni)
                        acc[g][mi][ni] = __builtin_amdgcn_mfma_f32_16x16x32_bf16(
                            areg[mi], breg[g][ni], acc[g][mi][ni], 0, 0, 0);
        }
        __syncthreads();
        cur ^= 1;
    }

#pragma unroll
    for (int ni = 0; ni < 2; ++ni) {
        int col = bncol + wn + ni * 16 + lm;
        float bi = bx1[col]        + bx2[col];
        float bo = bx1[col + 512]  + bx2[col + 512];
        float bu = bx1[col + 1024] + bx2[col + 1024];
#pragma unroll
        for (int mi = 0; mi < 2; ++mi) {
            int rbase = bm + wm + mi * 16 + quad * 4;
            float hsum = 0.f;
#pragma unroll
            for (int r = 0; r < 4; ++r) {
                int row = rbase + r;
                if (row < E) {
                    float ax  = (float)xout[(size_t)row * 2048 + col];
                    float aox = (float)xout[(size_t)row * 2048 + 512 + col];
                    float aux = (float)xout[(size_t)row * 2048 + 1024 + col];
                    float i_ = sigmoidf_(acc[0][mi][ni][r] + ax + bi);
                    float o_ = sigmoidf_(acc[1][mi][ni][r] + aox + bo);
                    float u_ = tanhf_(acc[2][mi][ni][r] + aux + bu);
                    float c  = i_ * u_ + fcsum[(size_t)row * 512 + col];
                    bf16 hb  = (bf16)(o_ * tanhf_(c));
                    cellout[(size_t)row * 512 + col] = (bf16)c;
                    hout[(size_t)row * 512 + col] = hb;
                    hsum += (float)hb;
                }
            }
            if (hsout && rbase < E)
                hsout[(size_t)(rbase >> 2) * 512 + col] = (bf16)hsum;
        }
    }
}

// ---------------------------------------------------------------------------
// tree_emb = column sum of node_emb, 3-stage parallel reduction
#define R1_BLOCKS 2048
#define R1_ROWS 43          // 2048*43 = 88064 >= 87381
__global__ void reduce1_kernel(const float* __restrict__ ne, float* __restrict__ partial)
{
    int t = threadIdx.x;
    int b = blockIdx.x;
    int r0 = b * R1_ROWS;
    int r1 = r0 + R1_ROWS; r1 = (r1 < NN) ? r1 : NN;
    float acc = 0.f;
    for (int r = r0; r < r1; ++r) acc += ne[(size_t)r * 256 + t];
    partial[(size_t)b * 256 + t] = acc;
}
__global__ void reduce2_kernel(const float* __restrict__ partial, float* __restrict__ partial2)
{
    int t = threadIdx.x;
    int b = blockIdx.x;      // 0..63
    float acc = 0.f;
    for (int i = 0; i < 32; ++i) acc += partial[(size_t)(b * 32 + i) * 256 + t];
    partial2[(size_t)b * 256 + t] = acc;
}
__global__ void reduce3_kernel(const float* __restrict__ partial2, float* __restrict__ tree)
{
    int t = threadIdx.x;
    float acc = 0.f;
    for (int i = 0; i < 64; ++i) acc += partial2[(size_t)i * 256 + t];
    tree[t] = acc;
}

// ---------------------------------------------------------------------------
extern "C" void kernel_launch(void* const* d_in, const int* in_sizes, int n_in,
                              void* d_out, int out_size, void* d_ws, size_t ws_size,
                              hipStream_t stream)
{
    const float* x      = (const float*)d_in[0];
    const float* W_in   = (const float*)d_in[8];
    const float* b_in   = (const float*)d_in[9];
    const float* W_ioux = (const float*)d_in[10];
    const float* b_ioux = (const float*)d_in[11];
    const float* W_iouh = (const float*)d_in[12];
    const float* b_iouh = (const float*)d_in[13];
    const float* W_fx   = (const float*)d_in[14];
    const float* b_fx   = (const float*)d_in[15];
    const float* W_fh   = (const float*)d_in[16];
    const float* b_fh   = (const float*)d_in[17];
    const float* W_out  = (const float*)d_in[18];
    const float* b_out  = (const float*)d_in[19];

    static const int LS[10] = {0, 1, 5, 21, 85, 341, 1365, 5461, 21845, 87381};

    char* ws = (char*)d_ws;
    size_t off = 0;
    auto take = [&](size_t bytes) -> void* {
        void* p = ws + off;
        off += (bytes + 255) & ~(size_t)255;
        return p;
    };
    bf16*  wt_in      = (bf16*) take((size_t)512 * 512 * 2);
    bf16*  wt_out     = (bf16*) take((size_t)256 * 512 * 2);
    bf16*  wt_xcat    = (bf16*) take((size_t)2 * 2048 * 512 * 2);  // [W_ioux^T | W_fx^T]
    bf16*  wt_iouh    = (bf16*) take((size_t)2 * 1536 * 512 * 2);
    bf16*  wt_fh      = (bf16*) take((size_t)2 * 512 * 512 * 2);
    bf16*  h          = (bf16*) take((size_t)NN * 512 * 2);       // internal + leaf (ping A)
    bf16*  hint1      = (bf16*) take((size_t)NINT * 512 * 2);     // internal ping B
    bf16*  hB         = (bf16*) take((size_t)NLEAF * 512 * 2);    // leaf ping B
    // cells (bf16); contiguous span doubles as x-as-bf16 staging during inproj
    bf16*  cell_int   = (bf16*) take((size_t)NINT * 512 * 2);
    bf16*  cell_leaf  = (bf16*) take((size_t)NLEAF * 512 * 2);
    float* fcsum      = (float*)take((size_t)16384 * 512 * 4);
    bf16*  hsA        = (bf16*) take((size_t)16384 * 512 * 2);    // hs for d=7,5,3,1
    bf16*  hsB        = (bf16*) take((size_t)4096 * 512 * 2);     // hs for d=6,4,2,0
    bf16*  XOUT       = (bf16*) take((size_t)NINT * 2048 * 2);    // x-part preacts
    float* partial    = (float*)take((size_t)R1_BLOCKS * 256 * 4);
    float* partial2   = (float*)take((size_t)64 * 256 * 4);
    bf16*  xbf        = cell_int;   // NN*512 bf16 == cell_int+cell_leaf span

    dim3 blk(256), blk512(512);
    auto tgrid = [](int total) { return dim3((unsigned)((total + 255) / 256)); };

    // --- weight transpose+convert ---
    tconv_kernel<<<tgrid(512 * 512), blk, 0, stream>>>(W_in, wt_in, 512, 512 * 512);
    tconv_kernel<<<tgrid(256 * 512), blk, 0, stream>>>(W_out, wt_out, 256, 256 * 512);
    for (int l = 0; l < 2; ++l) {
        bf16* xc = wt_xcat + (size_t)l * 2048 * 512;
        tconv_kernel<<<tgrid(1536 * 512), blk, 0, stream>>>(
            W_ioux + (size_t)l * 512 * 1536, xc, 1536, 1536 * 512);
        tconv_kernel<<<tgrid(512 * 512), blk, 0, stream>>>(
            W_fx + (size_t)l * 512 * 512, xc + (size_t)1536 * 512, 512, 512 * 512);
        tconv_kernel<<<tgrid(1536 * 512), blk, 0, stream>>>(
            W_iouh + (size_t)l * 512 * 1536, wt_iouh + (size_t)l * 1536 * 512,
            1536, 1536 * 512);
        tconv_kernel<<<tgrid(512 * 512), blk, 0, stream>>>(
            W_fh + (size_t)l * 512 * 512, wt_fh + (size_t)l * 512 * 512,
            512, 512 * 512);
    }

    auto gemm = [&](const bf16* A, const bf16* Bt, int bstride, int K,
                    float* Cf, bf16* Cb, const float* b1, const float* b2,
                    int M, int N, int relu, int swz) {
        int mt = (M + 127) / 128, nt = N / 128;
        gemm_kernel<<<dim3((unsigned)(mt * nt)), blk512, 0, stream>>>(
            A, Bt, bstride, K, nt, Cf, Cb, b1, b2, M, N, relu, swz);
    };

    // --- input projection: h = relu(x @ W_in + b_in) (internal + leaf rows) ---
    convx_kernel<<<tgrid(NN * 128), blk, 0, stream>>>(x, xbf, NN * 128);
    gemm(xbf, wt_in, 512, 512, nullptr, h, b_in, nullptr, NN, 512, 1, 1);

    for (int l = 0; l < 2; ++l) {
        const bf16* wxc  = wt_xcat + (size_t)l * 2048 * 512;
        const bf16* wih  = wt_iouh + (size_t)l * 1536 * 512;
        const bf16* wfh  = wt_fh + (size_t)l * 512 * 512;
        const float* bx1 = b_ioux + (size_t)l * 1536;
        const float* bx2 = b_iouh + (size_t)l * 1536;
        const float* bf1 = b_fx + (size_t)l * 512;
        const float* bf2 = b_fh + (size_t)l * 512;

        const bf16* lin   = (l == 0) ? (h + (size_t)LEAF_START * 512) : hB;
        bf16*       lout  = (l == 0) ? hB : (h + (size_t)LEAF_START * 512);
        const bf16* hprev = (l == 0) ? h : hint1;
        bf16*       hcur  = (l == 0) ? hint1 : h;

        // big per-layer GEMM: XOUT[NINT x 2048] = hprev @ [W_ioux | W_fx]^T
        gemm(hprev, wxc, 512, 512, nullptr, XOUT, nullptr, nullptr,
             NINT, 2048, 0, 1);

        // leaves: fused 3-gate GEMM + cell epilogue; produces hs for d=7
        {
            int mt = NLEAF / 128;   // 512
            leaf_kernel<<<dim3((unsigned)(mt * 8)), blk512, 0, stream>>>(
                lin, wxc /* rows 0..1535 = W_ioux^T */, bx1, bx2,
                lout, cell_leaf, hsA, NLEAF, 1);
        }

        // levels 7..0 — ONE merged kernel per level (CF phase + IOU phase)
        for (int d = 7; d >= 0; --d) {
            int s  = LS[d];
            int E  = LS[d + 1] - LS[d];
            int cs = LS[d + 1];
            const bf16* hc = (d == 7) ? lout : (hcur + (size_t)cs * 512);
            const bf16* cc = (d == 7) ? cell_leaf : (cell_int + (size_t)cs * 512);
            bf16* hs_read  = (d & 1) ? hsA : hsB;              // from level d+1 (or leaf)
            bf16* hs_write = (d == 0) ? nullptr : ((d & 1) ? hsB : hsA);
            const bf16* xo = XOUT + (size_t)s * 2048;

            int mt = (E + 127) / 128;
            level_kernel<<<dim3((unsigned)(mt * 8)), blk512, 0, stream>>>(
                hs_read, hc, cc, wih, wfh, xo, bx1, bx2, bf1, bf2, fcsum,
                hcur + (size_t)s * 512, cell_int + (size_t)s * 512, hs_write, E, 1);
        }
    }

    // --- output projection + tree reduction ---
    float* node_emb = (float*)d_out;
    gemm(h, wt_out, 512, 512, node_emb, nullptr, b_out, nullptr, NN, 256, 0, 1);
    reduce1_kernel<<<dim3(R1_BLOCKS), blk, 0, stream>>>(node_emb, partial);
    reduce2_kernel<<<dim3(64), blk, 0, stream>>>(partial, partial2);
    reduce3_kernel<<<dim3(1), blk, 0, stream>>>(partial2, node_emb + (size_t)NN * 256);
}

// Round 19
// 1673.256 us; speedup vs baseline: 1.0945x; 1.0945x over previous
//
#include <hip/hip_runtime.h>

typedef __bf16 bf16;
typedef __bf16 bf16x8 __attribute__((ext_vector_type(8)));
typedef float f32x4 __attribute__((ext_vector_type(4)));

#define NN 87381
#define NINT 21845
#define NLEAF 65536
#define LEAF_START 21845

__device__ __forceinline__ float sigmoidf_(float x) {
    return 1.0f / (1.0f + __expf(-x));
}
__device__ __forceinline__ float tanhf_(float x) {
    return 1.0f - 2.0f / (__expf(2.0f * x) + 1.0f);
}

// async 16B global -> LDS (lane-contiguous dest required)
__device__ __forceinline__ void gload_lds16(const bf16* g, bf16* l) {
    __builtin_amdgcn_global_load_lds(
        (const __attribute__((address_space(1))) unsigned int*)g,
        (__attribute__((address_space(3))) unsigned int*)l, 16, 0, 0);
}

// Bijective XCD-chunked blockIdx swizzle (m204).
__device__ __forceinline__ int xcd_swz(int bid, int nwg) {
    int q = nwg >> 3, r = nwg & 7;
    int x = bid & 7, i = bid >> 3;
    return (x < r ? x * (q + 1) : r * (q + 1) + (x - r) * q) + i;
}

// XOR-swizzled LDS chunk index for (row, kchunk) on a [R][64] bf16 tile
// (conflict-free: R4/R8 measured SQ_LDS_BANK_CONFLICT == 0).
#define SWZ(r, kc) ((((r) << 3) | ((kc) ^ ((r) & 7))) << 3)

// ---------------------------------------------------------------------------
// W (512 x NR fp32, row-major) -> Wt (NR x 512 bf16)
__global__ void tconv_kernel(const float* __restrict__ W, bf16* __restrict__ Wt,
                             int NR, int total) {
    int idx = blockIdx.x * 256 + threadIdx.x;
    if (idx >= total) return;
    int n = idx >> 9;
    int k = idx & 511;
    Wt[idx] = (bf16)W[(size_t)k * NR + n];
}

// x fp32 -> bf16, vectorized (4 floats / thread)
__global__ void convx_kernel(const float* __restrict__ X, bf16* __restrict__ Y, int total4) {
    int idx = blockIdx.x * 256 + threadIdx.x;
    if (idx >= total4) return;
    const float4 f = *reinterpret_cast<const float4*>(X + (size_t)idx * 4);
    bf16 o[4] = {(bf16)f.x, (bf16)f.y, (bf16)f.z, (bf16)f.w};
    *reinterpret_cast<ushort2*>(Y + (size_t)idx * 4 + 0) = *reinterpret_cast<ushort2*>(&o[0]);
    *reinterpret_cast<ushort2*>(Y + (size_t)idx * 4 + 2) = *reinterpret_cast<ushort2*>(&o[2]);
}

// ---------------------------------------------------------------------------
// 2x4 MFMA compute core (8-wave blocks: wave tile 32 rows x 64 cols), K=64.
#define MFMA_COMPUTE_2x4(As, Bs, acc, wm, wn, lm, quad)                          \
    _Pragma("unroll")                                                            \
    for (int kk = 0; kk < 64; kk += 32) {                                        \
        const int kc_ = (kk >> 3) + quad;                                        \
        bf16x8 areg[2], breg[4];                                                 \
        _Pragma("unroll")                                                        \
        for (int mi = 0; mi < 2; ++mi)                                           \
            areg[mi] = *reinterpret_cast<const bf16x8*>(                         \
                &(As)[SWZ(wm + mi * 16 + lm, kc_)]);                             \
        _Pragma("unroll")                                                        \
        for (int ni = 0; ni < 4; ++ni)                                           \
            breg[ni] = *reinterpret_cast<const bf16x8*>(                         \
                &(Bs)[SWZ(wn + ni * 16 + lm, kc_)]);                             \
        _Pragma("unroll")                                                        \
        for (int mi = 0; mi < 2; ++mi)                                           \
            _Pragma("unroll")                                                    \
            for (int ni = 0; ni < 4; ++ni)                                       \
                acc[mi][ni] = __builtin_amdgcn_mfma_f32_16x16x32_bf16(           \
                    areg[mi], breg[ni], acc[mi][ni], 0, 0, 0);                   \
    }

// Plain GEMM: C[M x N] = A[M x K] @ Bt[N x K]^T + b1 + b2 (Bt ld = bstride).
// 512 threads / 8 waves, 128x128 block tile, wave tile 32x64 -> 32 acc regs.
// BK=64 double-buffered, hoisted staging pointers (advance by t*64).
__global__ __launch_bounds__(512)
void gemm_kernel(const bf16* __restrict__ A, const bf16* __restrict__ Bt,
                 int bstride, int K, int ntiles,
                 float* __restrict__ Cf, bf16* __restrict__ Cb,
                 const float* __restrict__ bias1, const float* __restrict__ bias2,
                 int M, int N, int relu, int swz)
{
    __shared__ __align__(16) bf16 As[2][128 * 64];
    __shared__ __align__(16) bf16 Bs[2][128 * 64];
    const int tid  = threadIdx.x;
    const int wave = tid >> 6;
    const int lane = tid & 63;
    int bid = blockIdx.x;
    if (swz) bid = xcd_swz(bid, (int)gridDim.x);
    const int bm = (bid / ntiles) * 128;
    const int bn = (bid % ntiles) * 128;
    const int wm = (wave & 3) * 32;
    const int wn = (wave >> 2) * 64;
    const int lm   = lane & 15;
    const int quad = lane >> 4;

    f32x4 acc[2][4];
#pragma unroll
    for (int i = 0; i < 2; ++i)
#pragma unroll
        for (int j = 0; j < 4; ++j) acc[i][j] = (f32x4){0.f, 0.f, 0.f, 0.f};

    // hoisted per-chunk staging pointers/offsets
    const bf16* aptr[2];
    const bf16* bptr[2];
    int loff[2];
#pragma unroll
    for (int i = 0; i < 2; ++i) {
        int c   = i * 512 + tid;           // 1024 chunks (128 rows x 8)
        int r   = c >> 3;
        int kc8 = ((c & 7) ^ (r & 7)) << 3;
        int gr  = bm + r; gr = (gr < M) ? gr : (M - 1);
        aptr[i] = A + (size_t)gr * K + kc8;
        bptr[i] = Bt + (size_t)(bn + r) * bstride + kc8;
        loff[i] = c << 3;
    }

    auto stage = [&](int buf, int t) {
        const int kofs = t << 6;
#pragma unroll
        for (int i = 0; i < 2; ++i)
            gload_lds16(aptr[i] + kofs, &As[0][0] + buf * (128 * 64) + loff[i]);
#pragma unroll
        for (int i = 0; i < 2; ++i)
            gload_lds16(bptr[i] + kofs, &Bs[0][0] + buf * (128 * 64) + loff[i]);
    };

    const int nk = K >> 6;
    stage(0, 0);
    __syncthreads();
    int cur = 0;
    for (int t = 0; t < nk; ++t) {
        if (t + 1 < nk) stage(cur ^ 1, t + 1);
        MFMA_COMPUTE_2x4(As[cur], Bs[cur], acc, wm, wn, lm, quad);
        __syncthreads();   // drains prefetch vmcnt AFTER compute
        cur ^= 1;
    }

#pragma unroll
    for (int ni = 0; ni < 4; ++ni) {
        int col = bn + wn + ni * 16 + lm;
        float bsum = (bias1 ? bias1[col] : 0.f) + (bias2 ? bias2[col] : 0.f);
#pragma unroll
        for (int mi = 0; mi < 2; ++mi) {
#pragma unroll
            for (int r = 0; r < 4; ++r) {
                int row = bm + wm + mi * 16 + quad * 4 + r;
                if (row < M) {
                    float v = acc[mi][ni][r] + bsum;
                    if (relu) v = (v > 0.f) ? v : 0.f;
                    if (Cf) Cf[(size_t)row * N + col] = v;
                    else    Cb[(size_t)row * N + col] = (bf16)v;
                }
            }
        }
    }
}

// ---------------------------------------------------------------------------
// Leaf kernel: fused 3-gate IOU GEMM (K=512) + cell epilogue + hs producer.
// A = leaf h rows; B = gate-major [1536][512] (W_ioux^T). Lean epilogue
// (no fcs/xout) measured 180 vs 201 us for the branchy variant (R18).
__global__ __launch_bounds__(512)
void leaf_kernel(const bf16* __restrict__ A, const bf16* __restrict__ wiou,
                 const float* __restrict__ bx1, const float* __restrict__ bx2,
                 bf16* __restrict__ hout, bf16* __restrict__ cellout,
                 bf16* __restrict__ hsout, int M, int swz)
{
    __shared__ __align__(16) bf16 As[2][128 * 64];
    __shared__ __align__(16) bf16 Bs[2][3 * 64 * 64];
    const int tid  = threadIdx.x;
    const int wave = tid >> 6;
    const int lane = tid & 63;
    int bid = blockIdx.x;
    if (swz) bid = xcd_swz(bid, (int)gridDim.x);
    const int bm = (bid >> 3) * 128;
    const int bn = (bid & 7) * 64;
    if (bm >= M) return;
    const int wm   = (wave & 3) * 32;
    const int wn   = (wave >> 2) * 32;
    const int lm   = lane & 15;
    const int quad = lane >> 4;

    f32x4 acc[3][2][2];
#pragma unroll
    for (int g = 0; g < 3; ++g)
#pragma unroll
        for (int i = 0; i < 2; ++i)
#pragma unroll
            for (int j = 0; j < 2; ++j) acc[g][i][j] = (f32x4){0.f, 0.f, 0.f, 0.f};

    const bf16* aptr[2];
    int aoff[2];
#pragma unroll
    for (int i = 0; i < 2; ++i) {
        int c   = i * 512 + tid;
        int r   = c >> 3;
        int kc8 = ((c & 7) ^ (r & 7)) << 3;
        int gr  = bm + r; gr = (gr < M) ? gr : (M - 1);
        aptr[i] = A + ((size_t)gr << 9) + kc8;
        aoff[i] = c << 3;
    }
    const bf16* bptr[3];
    int boff[3];
#pragma unroll
    for (int i = 0; i < 3; ++i) {
        int c   = i * 512 + tid;
        int g   = c >> 9;
        int cg  = c & 511;
        int r   = cg >> 3;
        int kc8 = ((cg & 7) ^ (r & 7)) << 3;
        bptr[i] = wiou + (size_t)(g * 512 + bn + r) * 512 + kc8;
        boff[i] = c << 3;
    }

    auto stage = [&](int buf, int t) {
        const int kofs = t << 6;
#pragma unroll
        for (int i = 0; i < 2; ++i)
            gload_lds16(aptr[i] + kofs, &As[0][0] + buf * (128 * 64) + aoff[i]);
#pragma unroll
        for (int i = 0; i < 3; ++i)
            gload_lds16(bptr[i] + kofs, &Bs[0][0] + buf * (3 * 64 * 64) + boff[i]);
    };

    stage(0, 0);
    __syncthreads();
    int cur = 0;
    for (int t = 0; t < 8; ++t) {
        if (t + 1 < 8) stage(cur ^ 1, t + 1);
#pragma unroll
        for (int kk = 0; kk < 64; kk += 32) {
            const int kc_ = (kk >> 3) + quad;
            bf16x8 areg[2];
#pragma unroll
            for (int mi = 0; mi < 2; ++mi)
                areg[mi] = *reinterpret_cast<const bf16x8*>(
                    &As[cur][SWZ(wm + mi * 16 + lm, kc_)]);
            bf16x8 breg[3][2];
#pragma unroll
            for (int g = 0; g < 3; ++g)
#pragma unroll
                for (int ni = 0; ni < 2; ++ni)
                    breg[g][ni] = *reinterpret_cast<const bf16x8*>(
                        &Bs[cur][g * 4096 + SWZ(wn + ni * 16 + lm, kc_)]);
#pragma unroll
            for (int g = 0; g < 3; ++g)
#pragma unroll
                for (int mi = 0; mi < 2; ++mi)
#pragma unroll
                    for (int ni = 0; ni < 2; ++ni)
                        acc[g][mi][ni] = __builtin_amdgcn_mfma_f32_16x16x32_bf16(
                            areg[mi], breg[g][ni], acc[g][mi][ni], 0, 0, 0);
        }
        __syncthreads();
        cur ^= 1;
    }

#pragma unroll
    for (int ni = 0; ni < 2; ++ni) {
        int col = bn + wn + ni * 16 + lm;
        float bi = bx1[col]        + bx2[col];
        float bo = bx1[col + 512]  + bx2[col + 512];
        float bu = bx1[col + 1024] + bx2[col + 1024];
#pragma unroll
        for (int mi = 0; mi < 2; ++mi) {
            int rbase = bm + wm + mi * 16 + quad * 4;
            float hsum = 0.f;
#pragma unroll
            for (int r = 0; r < 4; ++r) {
                int row = rbase + r;
                if (row < M) {
                    float i_ = sigmoidf_(acc[0][mi][ni][r] + bi);
                    float o_ = sigmoidf_(acc[1][mi][ni][r] + bo);
                    float u_ = tanhf_(acc[2][mi][ni][r] + bu);
                    float c  = i_ * u_;
                    bf16 hb  = (bf16)(o_ * tanhf_(c));
                    cellout[(size_t)row * 512 + col] = (bf16)c;
                    hout[(size_t)row * 512 + col] = hb;
                    hsum += (float)hb;
                }
            }
            if (hsout && rbase < M)
                hsout[(size_t)(rbase >> 2) * 512 + col] = (bf16)hsum;
        }
    }
}

// ---------------------------------------------------------------------------
// Internal IOU GEMM (K=512) + cell epilogue + hs producer (unconditional
// fcs/xout: internal levels always have both).
__global__ __launch_bounds__(512)
void iou_fused_kernel(const bf16* __restrict__ A, const bf16* __restrict__ wiou,
                      const float* __restrict__ bx1, const float* __restrict__ bx2,
                      const float* __restrict__ fcs, const bf16* __restrict__ xout,
                      bf16* __restrict__ hout, bf16* __restrict__ cellout,
                      bf16* __restrict__ hsout,
                      int M, int swz)
{
    __shared__ __align__(16) bf16 As[2][128 * 64];
    __shared__ __align__(16) bf16 Bs[2][3 * 64 * 64];
    const int tid  = threadIdx.x;
    const int wave = tid >> 6;
    const int lane = tid & 63;
    int bid = blockIdx.x;
    if (swz) bid = xcd_swz(bid, (int)gridDim.x);
    const int bm = (bid >> 3) * 128;
    const int bn = (bid & 7) * 64;
    if (bm >= M) return;
    const int wm   = (wave & 3) * 32;
    const int wn   = (wave >> 2) * 32;
    const int lm   = lane & 15;
    const int quad = lane >> 4;

    f32x4 acc[3][2][2];
#pragma unroll
    for (int g = 0; g < 3; ++g)
#pragma unroll
        for (int i = 0; i < 2; ++i)
#pragma unroll
            for (int j = 0; j < 2; ++j) acc[g][i][j] = (f32x4){0.f, 0.f, 0.f, 0.f};

    const bf16* aptr[2];
    int aoff[2];
#pragma unroll
    for (int i = 0; i < 2; ++i) {
        int c   = i * 512 + tid;
        int r   = c >> 3;
        int kc8 = ((c & 7) ^ (r & 7)) << 3;
        int gr  = bm + r; gr = (gr < M) ? gr : (M - 1);
        aptr[i] = A + ((size_t)gr << 9) + kc8;
        aoff[i] = c << 3;
    }
    const bf16* bptr[3];
    int boff[3];
#pragma unroll
    for (int i = 0; i < 3; ++i) {
        int c   = i * 512 + tid;
        int g   = c >> 9;
        int cg  = c & 511;
        int r   = cg >> 3;
        int kc8 = ((cg & 7) ^ (r & 7)) << 3;
        bptr[i] = wiou + (size_t)(g * 512 + bn + r) * 512 + kc8;
        boff[i] = c << 3;
    }

    auto stage = [&](int buf, int t) {
        const int kofs = t << 6;
#pragma unroll
        for (int i = 0; i < 2; ++i)
            gload_lds16(aptr[i] + kofs, &As[0][0] + buf * (128 * 64) + aoff[i]);
#pragma unroll
        for (int i = 0; i < 3; ++i)
            gload_lds16(bptr[i] + kofs, &Bs[0][0] + buf * (3 * 64 * 64) + boff[i]);
    };

    stage(0, 0);
    __syncthreads();
    int cur = 0;
    for (int t = 0; t < 8; ++t) {
        if (t + 1 < 8) stage(cur ^ 1, t + 1);
#pragma unroll
        for (int kk = 0; kk < 64; kk += 32) {
            const int kc_ = (kk >> 3) + quad;
            bf16x8 areg[2];
#pragma unroll
            for (int mi = 0; mi < 2; ++mi)
                areg[mi] = *reinterpret_cast<const bf16x8*>(
                    &As[cur][SWZ(wm + mi * 16 + lm, kc_)]);
            bf16x8 breg[3][2];
#pragma unroll
            for (int g = 0; g < 3; ++g)
#pragma unroll
                for (int ni = 0; ni < 2; ++ni)
                    breg[g][ni] = *reinterpret_cast<const bf16x8*>(
                        &Bs[cur][g * 4096 + SWZ(wn + ni * 16 + lm, kc_)]);
#pragma unroll
            for (int g = 0; g < 3; ++g)
#pragma unroll
                for (int mi = 0; mi < 2; ++mi)
#pragma unroll
                    for (int ni = 0; ni < 2; ++ni)
                        acc[g][mi][ni] = __builtin_amdgcn_mfma_f32_16x16x32_bf16(
                            areg[mi], breg[g][ni], acc[g][mi][ni], 0, 0, 0);
        }
        __syncthreads();
        cur ^= 1;
    }

#pragma unroll
    for (int ni = 0; ni < 2; ++ni) {
        int col = bn + wn + ni * 16 + lm;
        float bi = bx1[col]        + bx2[col];
        float bo = bx1[col + 512]  + bx2[col + 512];
        float bu = bx1[col + 1024] + bx2[col + 1024];
#pragma unroll
        for (int mi = 0; mi < 2; ++mi) {
            int rbase = bm + wm + mi * 16 + quad * 4;
            float hsum = 0.f;
#pragma unroll
            for (int r = 0; r < 4; ++r) {
                int row = rbase + r;
                if (row < M) {
                    float ax  = (float)xout[(size_t)row * 2048 + col];
                    float aox = (float)xout[(size_t)row * 2048 + 512 + col];
                    float aux = (float)xout[(size_t)row * 2048 + 1024 + col];
                    float i_ = sigmoidf_(acc[0][mi][ni][r] + ax + bi);
                    float o_ = sigmoidf_(acc[1][mi][ni][r] + aox + bo);
                    float u_ = tanhf_(acc[2][mi][ni][r] + aux + bu);
                    float c  = i_ * u_ + fcs[(size_t)row * 512 + col];
                    bf16 hb  = (bf16)(o_ * tanhf_(c));
                    cellout[(size_t)row * 512 + col] = (bf16)c;
                    hout[(size_t)row * 512 + col] = hb;
                    hsum += (float)hb;
                }
            }
            if (hsout && rbase < M)
                hsout[(size_t)(rbase >> 2) * 512 + col] = (bf16)hsum;
        }
    }
}

// ---------------------------------------------------------------------------
// CF GEMM (K=512, child h only) + fused f-gate epilogue.
// M = 4E child rows. Parent x-part preact read from xout[p][1536+col].
// Epilogue: quad*4+r = 4 consecutive children of one parent (per-lane):
//   fcs[p][col] = sum_r sigmoid(acc[r] + Pf[p][col] + b) * cellc[4p+r][col]
__global__ __launch_bounds__(512)
void cf_kernel(const bf16* __restrict__ hc, const bf16* __restrict__ cellc,
               const bf16* __restrict__ wfh, const bf16* __restrict__ xout,
               const float* __restrict__ bf1, const float* __restrict__ bf2,
               float* __restrict__ fcs, int E, int swz)
{
    const int M = 4 * E;
    __shared__ __align__(16) bf16 As[2][128 * 64];
    __shared__ __align__(16) bf16 Bs[2][128 * 64];
    const int tid  = threadIdx.x;
    const int wave = tid >> 6;
    const int lane = tid & 63;
    int bid = blockIdx.x;
    if (swz) bid = xcd_swz(bid, (int)gridDim.x);
    const int bm = (bid >> 2) * 128;
    const int bn = (bid & 3) * 128;
    if (bm >= M) return;
    const int wm   = (wave & 3) * 32;
    const int wn   = (wave >> 2) * 64;
    const int lm   = lane & 15;
    const int quad = lane >> 4;

    f32x4 acc[2][4];
#pragma unroll
    for (int i = 0; i < 2; ++i)
#pragma unroll
        for (int j = 0; j < 4; ++j) acc[i][j] = (f32x4){0.f, 0.f, 0.f, 0.f};

    const bf16* aptr[2];
    const bf16* bptr[2];
    int loff[2];
#pragma unroll
    for (int i = 0; i < 2; ++i) {
        int c   = i * 512 + tid;
        int r   = c >> 3;
        int kc8 = ((c & 7) ^ (r & 7)) << 3;
        int gr  = bm + r; gr = (gr < M) ? gr : (M - 1);
        aptr[i] = hc + ((size_t)gr << 9) + kc8;
        bptr[i] = wfh + (size_t)(bn + r) * 512 + kc8;
        loff[i] = c << 3;
    }

    auto stage = [&](int buf, int t) {
        const int kofs = t << 6;
#pragma unroll
        for (int i = 0; i < 2; ++i)
            gload_lds16(aptr[i] + kofs, &As[0][0] + buf * (128 * 64) + loff[i]);
#pragma unroll
        for (int i = 0; i < 2; ++i)
            gload_lds16(bptr[i] + kofs, &Bs[0][0] + buf * (128 * 64) + loff[i]);
    };

    stage(0, 0);
    __syncthreads();
    int cur = 0;
    for (int t = 0; t < 8; ++t) {
        if (t + 1 < 8) stage(cur ^ 1, t + 1);
        MFMA_COMPUTE_2x4(As[cur], Bs[cur], acc, wm, wn, lm, quad);
        __syncthreads();
        cur ^= 1;
    }

#pragma unroll
    for (int ni = 0; ni < 4; ++ni) {
        int col = bn + wn + ni * 16 + lm;
        float bsum = bf1[col] + bf2[col];
#pragma unroll
        for (int mi = 0; mi < 2; ++mi) {
            int R0 = bm + wm + mi * 16;
            if (R0 + quad * 4 < M) {
                int p = (R0 >> 2) + quad;
                float pf = (float)xout[(size_t)p * 2048 + 1536 + col] + bsum;
                float fc = 0.f;
#pragma unroll
                for (int r = 0; r < 4; ++r) {
                    int row = R0 + quad * 4 + r;
                    fc += sigmoidf_(acc[mi][ni][r] + pf) *
                          (float)cellc[(size_t)row * 512 + col];
                }
                fcs[(size_t)p * 512 + col] = fc;
            }
        }
    }
}

// ---------------------------------------------------------------------------
// tree_emb = column sum of node_emb, 3-stage parallel reduction
#define R1_BLOCKS 2048
#define R1_ROWS 43          // 2048*43 = 88064 >= 87381
__global__ void reduce1_kernel(const float* __restrict__ ne, float* __restrict__ partial)
{
    int t = threadIdx.x;
    int b = blockIdx.x;
    int r0 = b * R1_ROWS;
    int r1 = r0 + R1_ROWS; r1 = (r1 < NN) ? r1 : NN;
    float acc = 0.f;
    for (int r = r0; r < r1; ++r) acc += ne[(size_t)r * 256 + t];
    partial[(size_t)b * 256 + t] = acc;
}
__global__ void reduce2_kernel(const float* __restrict__ partial, float* __restrict__ partial2)
{
    int t = threadIdx.x;
    int b = blockIdx.x;      // 0..63
    float acc = 0.f;
    for (int i = 0; i < 32; ++i) acc += partial[(size_t)(b * 32 + i) * 256 + t];
    partial2[(size_t)b * 256 + t] = acc;
}
__global__ void reduce3_kernel(const float* __restrict__ partial2, float* __restrict__ tree)
{
    int t = threadIdx.x;
    float acc = 0.f;
    for (int i = 0; i < 64; ++i) acc += partial2[(size_t)i * 256 + t];
    tree[t] = acc;
}

// ---------------------------------------------------------------------------
extern "C" void kernel_launch(void* const* d_in, const int* in_sizes, int n_in,
                              void* d_out, int out_size, void* d_ws, size_t ws_size,
                              hipStream_t stream)
{
    const float* x      = (const float*)d_in[0];
    const float* W_in   = (const float*)d_in[8];
    const float* b_in   = (const float*)d_in[9];
    const float* W_ioux = (const float*)d_in[10];
    const float* b_ioux = (const float*)d_in[11];
    const float* W_iouh = (const float*)d_in[12];
    const float* b_iouh = (const float*)d_in[13];
    const float* W_fx   = (const float*)d_in[14];
    const float* b_fx   = (const float*)d_in[15];
    const float* W_fh   = (const float*)d_in[16];
    const float* b_fh   = (const float*)d_in[17];
    const float* W_out  = (const float*)d_in[18];
    const float* b_out  = (const float*)d_in[19];

    static const int LS[10] = {0, 1, 5, 21, 85, 341, 1365, 5461, 21845, 87381};

    char* ws = (char*)d_ws;
    size_t off = 0;
    auto take = [&](size_t bytes) -> void* {
        void* p = ws + off;
        off += (bytes + 255) & ~(size_t)255;
        return p;
    };
    bf16*  wt_in      = (bf16*) take((size_t)512 * 512 * 2);
    bf16*  wt_out     = (bf16*) take((size_t)256 * 512 * 2);
    bf16*  wt_xcat    = (bf16*) take((size_t)2 * 2048 * 512 * 2);  // [W_ioux^T | W_fx^T]
    bf16*  wt_iouh    = (bf16*) take((size_t)2 * 1536 * 512 * 2);
    bf16*  wt_fh      = (bf16*) take((size_t)2 * 512 * 512 * 2);
    bf16*  h          = (bf16*) take((size_t)NN * 512 * 2);       // internal + leaf (ping A)
    bf16*  hint1      = (bf16*) take((size_t)NINT * 512 * 2);     // internal ping B
    bf16*  hB         = (bf16*) take((size_t)NLEAF * 512 * 2);    // leaf ping B
    // cells (bf16); contiguous span doubles as x-as-bf16 staging during inproj
    bf16*  cell_int   = (bf16*) take((size_t)NINT * 512 * 2);
    bf16*  cell_leaf  = (bf16*) take((size_t)NLEAF * 512 * 2);
    float* fcsum      = (float*)take((size_t)16384 * 512 * 4);
    bf16*  hsA        = (bf16*) take((size_t)16384 * 512 * 2);    // hs for d=7,5,3,1
    bf16*  hsB        = (bf16*) take((size_t)4096 * 512 * 2);     // hs for d=6,4,2,0
    bf16*  XOUT       = (bf16*) take((size_t)NINT * 2048 * 2);    // x-part preacts
    float* partial    = (float*)take((size_t)R1_BLOCKS * 256 * 4);
    float* partial2   = (float*)take((size_t)64 * 256 * 4);
    bf16*  xbf        = cell_int;   // NN*512 bf16 == cell_int+cell_leaf span

    dim3 blk(256), blk512(512);
    auto tgrid = [](int total) { return dim3((unsigned)((total + 255) / 256)); };

    // --- weight transpose+convert ---
    tconv_kernel<<<tgrid(512 * 512), blk, 0, stream>>>(W_in, wt_in, 512, 512 * 512);
    tconv_kernel<<<tgrid(256 * 512), blk, 0, stream>>>(W_out, wt_out, 256, 256 * 512);
    for (int l = 0; l < 2; ++l) {
        bf16* xc = wt_xcat + (size_t)l * 2048 * 512;
        tconv_kernel<<<tgrid(1536 * 512), blk, 0, stream>>>(
            W_ioux + (size_t)l * 512 * 1536, xc, 1536, 1536 * 512);
        tconv_kernel<<<tgrid(512 * 512), blk, 0, stream>>>(
            W_fx + (size_t)l * 512 * 512, xc + (size_t)1536 * 512, 512, 512 * 512);
        tconv_kernel<<<tgrid(1536 * 512), blk, 0, stream>>>(
            W_iouh + (size_t)l * 512 * 1536, wt_iouh + (size_t)l * 1536 * 512,
            1536, 1536 * 512);
        tconv_kernel<<<tgrid(512 * 512), blk, 0, stream>>>(
            W_fh + (size_t)l * 512 * 512, wt_fh + (size_t)l * 512 * 512,
            512, 512 * 512);
    }

    auto gemm = [&](const bf16* A, const bf16* Bt, int bstride, int K,
                    float* Cf, bf16* Cb, const float* b1, const float* b2,
                    int M, int N, int relu, int swz) {
        int mt = (M + 127) / 128, nt = N / 128;
        gemm_kernel<<<dim3((unsigned)(mt * nt)), blk512, 0, stream>>>(
            A, Bt, bstride, K, nt, Cf, Cb, b1, b2, M, N, relu, swz);
    };

    // --- input projection: h = relu(x @ W_in + b_in) (internal + leaf rows) ---
    convx_kernel<<<tgrid(NN * 128), blk, 0, stream>>>(x, xbf, NN * 128);
    gemm(xbf, wt_in, 512, 512, nullptr, h, b_in, nullptr, NN, 512, 1, 1);

    for (int l = 0; l < 2; ++l) {
        const bf16* wxc  = wt_xcat + (size_t)l * 2048 * 512;
        const bf16* wih  = wt_iouh + (size_t)l * 1536 * 512;
        const bf16* wfh  = wt_fh + (size_t)l * 512 * 512;
        const float* bx1 = b_ioux + (size_t)l * 1536;
        const float* bx2 = b_iouh + (size_t)l * 1536;
        const float* bf1 = b_fx + (size_t)l * 512;
        const float* bf2 = b_fh + (size_t)l * 512;

        const bf16* lin   = (l == 0) ? (h + (size_t)LEAF_START * 512) : hB;
        bf16*       lout  = (l == 0) ? hB : (h + (size_t)LEAF_START * 512);
        const bf16* hprev = (l == 0) ? h : hint1;
        bf16*       hcur  = (l == 0) ? hint1 : h;

        // big per-layer GEMM: XOUT[NINT x 2048] = hprev @ [W_ioux | W_fx]^T
        gemm(hprev, wxc, 512, 512, nullptr, XOUT, nullptr, nullptr,
             NINT, 2048, 0, 1);

        // leaves: lean fused 3-gate GEMM + cell epilogue; produces hs for d=7
        {
            int mt = NLEAF / 128;   // 512
            leaf_kernel<<<dim3((unsigned)(mt * 8)), blk512, 0, stream>>>(
                lin, wxc /* rows 0..1535 = W_ioux^T */, bx1, bx2,
                lout, cell_leaf, hsA, NLEAF, 1);
        }

        // levels 7..0 — split cf + iou (best-measured structure, R17)
        for (int d = 7; d >= 0; --d) {
            int s  = LS[d];
            int E  = LS[d + 1] - LS[d];
            int cs = LS[d + 1];
            const bf16* hc = (d == 7) ? lout : (hcur + (size_t)cs * 512);
            const bf16* cc = (d == 7) ? cell_leaf : (cell_int + (size_t)cs * 512);
            bf16* hs_read  = (d & 1) ? hsA : hsB;              // from level d+1 (or leaf)
            bf16* hs_write = (d == 0) ? nullptr : ((d & 1) ? hsB : hsA);
            const bf16* xo = XOUT + (size_t)s * 2048;

            int mt_cf = (4 * E + 127) / 128;
            cf_kernel<<<dim3((unsigned)(mt_cf * 4)), blk512, 0, stream>>>(
                hc, cc, wfh, xo, bf1, bf2, fcsum, E, 1);

            int mt_iou = (E + 127) / 128;
            iou_fused_kernel<<<dim3((unsigned)(mt_iou * 8)), blk512, 0, stream>>>(
                hs_read, wih, bx1, bx2, fcsum, xo,
                hcur + (size_t)s * 512, cell_int + (size_t)s * 512, hs_write, E, 1);
        }
    }

    // --- output projection + tree reduction ---
    float* node_emb = (float*)d_out;
    gemm(h, wt_out, 512, 512, node_emb, nullptr, b_out, nullptr, NN, 256, 0, 1);
    reduce1_kernel<<<dim3(R1_BLOCKS), blk, 0, stream>>>(node_emb, partial);
    reduce2_kernel<<<dim3(64), blk, 0, stream>>>(partial, partial2);
    reduce3_kernel<<<dim3(1), blk, 0, stream>>>(partial2, node_emb + (size_t)NN * 256);
}